// Round 5
// baseline (3942.019 us; speedup 1.0000x reference)
//
#include <hip/hip_runtime.h>
#include <stdint.h>

// ---------------------------------------------------------------------------
// 2-layer GRU, B=128, T=1024, H=IN=256, OUT=128.  Dtype probed on device.
//
// v10: v6 topology + v8's (correctness-verified) MFMA core.
//  - Topology/protocol byte-compatible with v6/v9 (best: 2662us): 256 blocks
//    x 512 thr, roles L0X/L0H/L1X/L1H x 64 batch-pairs, 4-slot rings with
//    in-band 8B {f16 sr,sz | f16 sn, tag16} relaxed-agent atomics, progress
//    counters, one lgkm-only barrier/step, v6 skewed LDS staging.
//  - Compute core: GEMV -> mfma_f32_16x16x32_f16 with M=2 (batch pair) in a
//    16-row tile.  Rows 2..15 are garbage-in/garbage-out (never read).  Per
//    block-step: 8 waves x 48 MFMA = 384 (~466 cyc/SIMD matrix pipe) vs
//    v9's 1536 cyc VALU dots + ~1100 cyc overhead (accvgpr reads etc).
//    Weights live as MFMA B-frags: AGPR residency is FREE for MFMA operands
//    -> the v6/v7/v9 accvgpr_read storm is deleted by construction.
//  - All operands f16 (bf16->f16 exact at these magnitudes; h stays f16 as
//    in v6; MFMA accumulates f32 = better than v6's fdot2 path).
//  - Frag conventions exactly as v8 (which PASSED): A row-major row=lane&15,
//    8 consecutive k at 8*(lane>>4); B row = W row (s = A.W^T); D col=lane&15,
//    row=4*(lane>>4)+i (m89).
// ---------------------------------------------------------------------------

#define NPAIR 64

// ws layout in dwords (unchanged from v6)
#define XR0_OFF 0            // uint2 [64][4][512]  (262144 dw)
#define XR1_OFF 262144       // uint2 [64][4][512]
#define HR0_OFF 524288       // uint2 [64][4][256]  (131072 dw)
#define CTR_OFF 655360       // u32   [4][64][16]
#define FLG_OFF 659456

#if defined(__has_builtin)
#if __has_builtin(__builtin_amdgcn_fdot2)
#define USE_DOT2 1
#endif
#if __has_builtin(__builtin_amdgcn_rcpf)
#define USE_RCP 1
#endif
#endif

typedef _Float16 half8 __attribute__((ext_vector_type(8)));
typedef float    f32x4 __attribute__((ext_vector_type(4)));
typedef _Float16 h2_t  __attribute__((ext_vector_type(2)));
union H2U { uint32_t u; h2_t h; };
union FU  { uint32_t u; float f; };

__device__ __forceinline__ float bf2f(uint16_t b){ FU v; v.u=(uint32_t)b<<16; return v.f; }
__device__ __forceinline__ uint16_t f2bf(float f){
    FU v; v.f=f; uint32_t r=v.u+0x7fffu+((v.u>>16)&1u); return (uint16_t)(r>>16);
}
__device__ __forceinline__ float rcp_f(float x){
#ifdef USE_RCP
    return __builtin_amdgcn_rcpf(x);
#else
    return 1.0f/x;
#endif
}
__device__ __forceinline__ float sigmoid_f(float x){ return rcp_f(1.0f+__expf(-x)); }
__device__ __forceinline__ float tanh_f(float x){
    float ax=fabsf(x); float e=__expf(-2.0f*ax);
    float t=(1.0f-e)*rcp_f(1.0f+e); return x<0.0f?-t:t;
}
// bf16 pair (packed u32) -> f16 pair (exact for |x| < 65504)
__device__ __forceinline__ uint32_t bfpair_to_h2(uint32_t raw){
    FU lo,hi; lo.u=raw<<16; hi.u=raw&0xffff0000u;
    H2U r; r.h[0]=(_Float16)lo.f; r.h[1]=(_Float16)hi.f; return r.u;
}
__device__ __forceinline__ uint32_t f2_to_h2(float a, float b){
    H2U r; r.h[0]=(_Float16)a; r.h[1]=(_Float16)b; return r.u;
}
__device__ __forceinline__ float hbits2f(uint32_t bits){
    H2U t; t.u = bits & 0xffffu; return (float)t.h[0];
}
// f16-pair dot (epilogue only)
__device__ __forceinline__ float dot2acc(uint32_t w, uint32_t v, float acc){
#ifdef USE_DOT2
    H2U a,b; a.u=w; b.u=v;
    return __builtin_amdgcn_fdot2(a.h, b.h, acc, false);
#else
    H2U a,b; a.u=w; b.u=v;
    return fmaf((float)a.h[1],(float)b.h[1], fmaf((float)a.h[0],(float)b.h[0],acc));
#endif
}

#define RLX_LD(p)    __hip_atomic_load((p),        __ATOMIC_RELAXED, __HIP_MEMORY_SCOPE_AGENT)
#define RLX_ST(p,v)  __hip_atomic_store((p), (v),  __ATOMIC_RELAXED, __HIP_MEMORY_SCOPE_AGENT)
__device__ __forceinline__ uint64_t RLX_LD64(const uint64_t* p){
    return __hip_atomic_load(p, __ATOMIC_RELAXED, __HIP_MEMORY_SCOPE_AGENT);
}
__device__ __forceinline__ void RLX_ST64(uint64_t* p, uint64_t v){
    __hip_atomic_store(p, v, __ATOMIC_RELAXED, __HIP_MEMORY_SCOPE_AGENT);
}

// LDS-only barrier (ring publishes drain under compute; rings tag-protected)
#define BAR() do {                                              \
    asm volatile("s_waitcnt lgkmcnt(0)" ::: "memory");          \
    __builtin_amdgcn_s_barrier();                               \
    asm volatile("" ::: "memory");                              \
} while (0)

__device__ __forceinline__ f32x4 MFMA16(uint4 a, uint4 b, f32x4 c){
    half8 A = __builtin_bit_cast(half8, a);
    half8 B = __builtin_bit_cast(half8, b);
    return __builtin_amdgcn_mfma_f32_16x16x32_f16(A, B, c, 0, 0, 0);
}

// B-frag: 8 consecutive k (f16) of weight row `row`
__device__ __forceinline__ uint4 ldfrag16(const void* W, int isbf, int row, int k0){
    if (isbf){
        uint4 raw = *(const uint4*)((const uint16_t*)W + (size_t)row*256 + k0);
        raw.x = bfpair_to_h2(raw.x); raw.y = bfpair_to_h2(raw.y);
        raw.z = bfpair_to_h2(raw.z); raw.w = bfpair_to_h2(raw.w);
        return raw;
    } else {
        const float* p = (const float*)W + (size_t)row*256 + k0;
        uint4 r;
        r.x = f2_to_h2(p[0],p[1]); r.y = f2_to_h2(p[2],p[3]);
        r.z = f2_to_h2(p[4],p[5]); r.w = f2_to_h2(p[6],p[7]);
        return r;
    }
}

__global__ void probe_init(const uint32_t* __restrict__ w,
                           uint32_t* __restrict__ ctr,
                           uint32_t* __restrict__ flag) {
    int i = threadIdx.x;
    for (int k = i; k < 4096; k += 1024) ctr[k] = 0u;
    if (i == 0) {
        int c = 0;
        for (int j = 0; j < 64; ++j) {
            uint32_t e = (w[j] >> 7) & 0xFFu;
            c += (e >= 0x60u && e <= 0x7Cu) ? 1 : 0;
        }
        flag[0] = (c >= 32) ? 1u : 0u;
    }
}

__global__ void __launch_bounds__(512) __attribute__((amdgpu_waves_per_eu(2, 2)))
gru11(const void* __restrict__ xin,
      const void* __restrict__ Wx0, const void* __restrict__ bx0,
      const void* __restrict__ Wh0, const void* __restrict__ bh0,
      const void* __restrict__ Wx1, const void* __restrict__ bx1,
      const void* __restrict__ Wh1, const void* __restrict__ bh1,
      const void* __restrict__ Wo,  const void* __restrict__ bo,
      void* __restrict__ out,
      uint32_t* __restrict__ ws)
{
    const int tid  = threadIdx.x;
    const int pair = blockIdx.x & (NPAIR - 1);
    const int role = blockIdx.x >> 6;
    const int w    = tid >> 6;       // wave 0..7 -> units [32w, 32w+32)
    const int l    = tid & 63;
    const int lr   = l & 15;         // A-row / D-col
    const int lq   = l >> 4;         // k-subgroup / D-row-group

    uint64_t* XR0p = (uint64_t*)(ws + XR0_OFF) + pair * 2048;   // 4 slots x 512
    uint64_t* XR1p = (uint64_t*)(ws + XR1_OFF) + pair * 2048;
    uint64_t* HRp  = (uint64_t*)(ws + HR0_OFF) + pair * 1024;   // 4 slots x 256
    uint32_t* CTR  = ws + CTR_OFF;
    const int isbf = (int)ws[FLG_OFF];

    uint32_t* myprg   = CTR + role * 1024 + pair * 16;
    uint32_t* consprg = CTR + (role + 1) * 1024 + pair * 16;

    const void* Wsel; const void* bsel;
    if      (role == 0) { Wsel = Wx0; bsel = bx0; }
    else if (role == 1) { Wsel = Wh0; bsel = bh0; }
    else if (role == 2) { Wsel = Wx1; bsel = bx1; }
    else                { Wsel = Wh1; bsel = bh1; }

    // 48 B-frags: [g*2+m][kk], row = g*256 + 32w + 16m + lr, k0 = 32kk + 8lq
    uint4 bfr[6][8];
    float bias[6];
#pragma unroll
    for (int g = 0; g < 3; ++g)
#pragma unroll
        for (int m = 0; m < 2; ++m) {
            int row = g * 256 + 32 * w + 16 * m + lr;
            bias[g*2+m] = isbf ? bf2f(((const uint16_t*)bsel)[row])
                               : ((const float*)bsel)[row];
#pragma unroll
            for (int kk = 0; kk < 8; ++kk)
                bfr[g*2+m][kk] = ldfrag16(Wsel, isbf, row, 32*kk + 8*lq);
        }

    // v6 skewed LDS: 2 buffers x (2 x 136-dw batch halves)
    __shared__ __align__(16) uint32_t sb[544];

    if (role == 0 || role == 2) {
        // ------------------------------ X stages ---------------------------
        const uint32_t* xs32 = (const uint32_t*)xin;
        const float2*   xsf  = (const float2*)xin;
        const int bglob = pair * 2 + (tid >> 7);
        const int i128  = tid & 127;
        const int spos  = (tid >> 7) * 136 + i128 + ((i128 >> 6) << 2);
        uint32_t xpref = 0;
        uint2 pfh; pfh.x = 0; pfh.y = 0;
        if (role == 0 && tid < 256) {
            if (isbf) xpref = bfpair_to_h2(xs32[(size_t)bglob * 131072 + i128]);
            else { float2 f = xsf[(size_t)bglob * 131072 + i128]; xpref = f2_to_h2(f.x, f.y); }
        }
        uint64_t* outring = (role == 0) ? XR0p : XR1p;
        uint32_t prog_seen = 0;

        for (int t = 0; t < 1024; ++t) {
            if (t >= 4 && prog_seen + 3 < (uint32_t)t) {     // ring-wrap guard
                do { prog_seen = RLX_LD(consprg);
                     if (prog_seen + 3 < (uint32_t)t) __builtin_amdgcn_s_sleep(2);
                } while (prog_seen + 3 < (uint32_t)t);
            }
            if (tid < 256) {
                uint32_t pk;
                if (role == 0) pk = xpref;
                else {
                    uint2 v = pfh;
                    const uint32_t want = (uint32_t)(t + 1);
                    if (v.y != want) {
                        const uint64_t* a = HRp + (t & 3) * 256 + tid;
                        uint64_t u;
                        do { u = RLX_LD64(a);
                             v.x = (uint32_t)u; v.y = (uint32_t)(u >> 32);
                             if (v.y != want) __builtin_amdgcn_s_sleep(1);
                        } while (v.y != want);
                    }
                    pk = v.x;
                }
                sb[(t & 1) * 272 + spos] = pk;
            }
            BAR();
            if (tid == 0 && !(t & 1)) RLX_ST(myprg, (uint32_t)t);
            if (tid < 256 && t < 1023) {                     // prefetch t+1
                if (role == 0) {
                    if (isbf) xpref = bfpair_to_h2(xs32[(size_t)bglob * 131072 + (t+1)*128 + i128]);
                    else { float2 f = xsf[(size_t)bglob * 131072 + (t+1)*128 + i128]; xpref = f2_to_h2(f.x, f.y); }
                } else {
                    uint64_t u = RLX_LD64(HRp + ((t + 1) & 3) * 256 + tid);
                    pfh.x = (uint32_t)u; pfh.y = (uint32_t)(u >> 32);
                }
            }
            // A-frags (rows 0,1 = batch pair; rows 2..15 read batch lr&1: harmless)
            const uint32_t* abase = &sb[(t & 1) * 272 + (lr & 1) * 136];
            uint4 afr[8];
#pragma unroll
            for (int kk = 0; kk < 8; ++kk) {
                int j0 = 16*kk + 4*lq;
                afr[kk] = *(const uint4*)&abase[j0 + ((j0 >> 6) << 2)];
            }
            f32x4 acc[6];
#pragma unroll
            for (int i6 = 0; i6 < 6; ++i6)
                acc[i6] = (f32x4){bias[i6], bias[i6], bias[i6], bias[i6]};
#pragma unroll
            for (int kk = 0; kk < 8; ++kk)
#pragma unroll
                for (int i6 = 0; i6 < 6; ++i6)
                    acc[i6] = MFMA16(afr[kk], bfr[i6][kk], acc[i6]);
            // publish: valid D rows 0,1 live in lanes lq==0, regs 0,1
            if (lq == 0) {
                const uint32_t want = (uint32_t)(t + 1);
#pragma unroll
                for (int m = 0; m < 2; ++m) {
                    int u = 32 * w + 16 * m + lr;
#pragma unroll
                    for (int b = 0; b < 2; ++b) {
                        H2U lo; lo.h[0] = (_Float16)acc[m][b]; lo.h[1] = (_Float16)acc[2+m][b];
                        H2U hn; hn.u = 0; hn.h[0] = (_Float16)acc[4+m][b];
                        uint32_t hi = (hn.u & 0xFFFFu) | (want << 16);
                        RLX_ST64(outring + (t & 3) * 512 + 2 * u + b,
                                 (uint64_t)lo.u | ((uint64_t)hi << 32));
                    }
                }
            }
        }
        BAR();
        if (tid == 0) RLX_ST(myprg, 1024u);
    } else {
        // ------------------------------ H stages ---------------------------
        const uint64_t* xr64 = (role == 1) ? XR0p : XR1p;
        for (int i = tid; i < 544; i += 512) sb[i] = 0u;   // h(0) = 0
        float hreg[2][2] = {{0.f,0.f},{0.f,0.f}};
        uint64_t cur[4]; cur[0]=cur[1]=cur[2]=cur[3]=0;
        uint32_t prog_seen = 0;

        for (int t = 0; t < 1024; ++t) {
            if (role == 1 && t >= 4 && prog_seen + 3 < (uint32_t)t) {
                do { prog_seen = RLX_LD(consprg);
                     if (prog_seen + 3 < (uint32_t)t) __builtin_amdgcn_s_sleep(2);
                } while (prog_seen + 3 < (uint32_t)t);
            }
            const uint32_t want = (uint32_t)(t + 1);
            if (lq == 0) {               // consume 4 ring entries (prefetched)
#pragma unroll
                for (int m = 0; m < 2; ++m)
#pragma unroll
                    for (int b = 0; b < 2; ++b) {
                        int e = m * 2 + b;
                        int u = 32 * w + 16 * m + lr;
                        if ((uint32_t)(cur[e] >> 48) != want) {
                            const uint64_t* a = xr64 + (t & 3) * 512 + 2 * u + b;
                            uint64_t uu;
                            do { uu = RLX_LD64(a);
                                 if ((uint32_t)(uu >> 48) != want) __builtin_amdgcn_s_sleep(1);
                            } while ((uint32_t)(uu >> 48) != want);
                            cur[e] = uu;
                        }
                    }
            }
            BAR();                       // h(t) LDS writes (prev iter) visible
            if (tid == 0 && !(t & 1)) RLX_ST(myprg, (uint32_t)t);
            float srv[4], szv[4], snv[4];
            if (lq == 0) {
#pragma unroll
                for (int e = 0; e < 4; ++e) {
                    uint32_t loq = (uint32_t)cur[e];
                    srv[e] = hbits2f(loq);
                    szv[e] = hbits2f(loq >> 16);
                    snv[e] = hbits2f((uint32_t)(cur[e] >> 32));
                }
                if (t < 1023) {          // prefetch t+1
#pragma unroll
                    for (int m = 0; m < 2; ++m)
#pragma unroll
                        for (int b = 0; b < 2; ++b) {
                            int u = 32 * w + 16 * m + lr;
                            cur[m*2+b] = RLX_LD64(xr64 + ((t + 1) & 3) * 512 + 2 * u + b);
                        }
                }
            }
            // A-frags from h LDS
            const uint32_t* abase = &sb[(t & 1) * 272 + (lr & 1) * 136];
            uint4 afr[8];
#pragma unroll
            for (int kk = 0; kk < 8; ++kk) {
                int j0 = 16*kk + 4*lq;
                afr[kk] = *(const uint4*)&abase[j0 + ((j0 >> 6) << 2)];
            }
            f32x4 acc[6];
#pragma unroll
            for (int i6 = 0; i6 < 6; ++i6)
                acc[i6] = (f32x4){bias[i6], bias[i6], bias[i6], bias[i6]};
#pragma unroll
            for (int kk = 0; kk < 8; ++kk)
#pragma unroll
                for (int i6 = 0; i6 < 6; ++i6)
                    acc[i6] = MFMA16(afr[kk], bfr[i6][kk], acc[i6]);
            // activation + h update + LDS write (+ HR publish for role 1)
            if (lq == 0) {
#pragma unroll
                for (int m = 0; m < 2; ++m)
#pragma unroll
                    for (int b = 0; b < 2; ++b) {
                        int e = m * 2 + b;
                        float r = sigmoid_f(srv[e] + acc[m][b]);
                        float z = sigmoid_f(szv[e] + acc[2+m][b]);
                        float n = tanh_f  (snv[e] + r * acc[4+m][b]);
                        hreg[m][b] = z * hreg[m][b] + (1.0f - z) * n;
                    }
#pragma unroll
                for (int m = 0; m < 2; ++m)
#pragma unroll
                    for (int b = 0; b < 2; ++b) {
                        float hp = __shfl_xor(hreg[m][b], 1);
                        if (!(l & 1)) {  // even lane packs (h[u], h[u+1])
                            uint32_t pk = f2_to_h2(hreg[m][b], hp);
                            int j = 16 * w + 8 * m + (lr >> 1);
                            sb[((t + 1) & 1) * 272 + b * 136 + j + ((j >> 6) << 2)] = pk;
                            if (role == 1)
                                RLX_ST64(HRp + (t & 3) * 256 + b * 128 + j,
                                         (uint64_t)pk | ((uint64_t)want << 32));
                        }
                    }
            }
        }
        BAR();
        if (tid == 0) RLX_ST(myprg, 1024u);

        // ---------------- epilogue (role 3): out = h1.Wo^T + bo ------------
        if (role == 3 && tid < 256) {
            const int j = tid >> 1, bb = tid & 1;
            const uint32_t* hv = &sb[bb * 136];     // final h1 in buffer 0
            float acc;
            if (isbf) {
                acc = bf2f(((const uint16_t*)bo)[j]);
                const uint32_t* wo = (const uint32_t*)Wo + j * 128;
#pragma unroll 8
                for (int c = 0; c < 128; ++c)
                    acc = dot2acc(bfpair_to_h2(wo[c]), hv[c + ((c >> 6) << 2)], acc);
                ((uint16_t*)out)[(pair * 2 + bb) * 128 + j] = f2bf(acc);
            } else {
                acc = ((const float*)bo)[j];
                const float2* wo = (const float2*)Wo + j * 128;
#pragma unroll 8
                for (int c = 0; c < 128; ++c) {
                    float2 f = wo[c];
                    acc = dot2acc(f2_to_h2(f.x, f.y), hv[c + ((c >> 6) << 2)], acc);
                }
                ((float*)out)[(pair * 2 + bb) * 128 + j] = acc;
            }
        }
    }
}

extern "C" void kernel_launch(void* const* d_in, const int* in_sizes, int n_in,
                              void* d_out, int out_size, void* d_ws, size_t ws_size,
                              hipStream_t stream) {
    uint32_t* ws  = (uint32_t*)d_ws;
    uint32_t* CTR = ws + CTR_OFF;
    uint32_t* FLG = ws + FLG_OFF;

    probe_init<<<dim3(1), dim3(1024), 0, stream>>>((const uint32_t*)d_in[1], CTR, FLG);
    gru11<<<dim3(256), dim3(512), 0, stream>>>(
        d_in[0], d_in[1], d_in[2], d_in[3], d_in[4],
        d_in[5], d_in[6], d_in[7], d_in[8], d_in[9], d_in[10],
        d_out, ws);
}